// Round 1
// baseline (637.242 us; speedup 1.0000x reference)
//
#include <hip/hip_runtime.h>
#include <hip/hip_bf16.h>
#include <math.h>

// Problem constants (B,S,H,D fixed by the reference setup_inputs)
#define SLEN 2048
#define NH   12
#define NB   2
#define DH   64
#define IT   64          // i-rows per block
#define JT   64          // j-cols per LDS tile
#define LDK  72          // padded LDS row length in elements (+8 bf16 = +16B: bank-conflict-free, keeps 16B alignment)
#define NWAVE 4

typedef __bf16 bfx8 __attribute__((ext_vector_type(8)));
typedef float  f32x4 __attribute__((ext_vector_type(4)));

// Stage a 64x64 fp32 tile from qkv (slice t in {0=q,1=k}) with rotary applied,
// converted to bf16, into dst[row][d] with row stride LDK.
__device__ __forceinline__ void stage_rot(const float* __restrict__ qkv,
                                          const float* __restrict__ cosb,
                                          const float* __restrict__ sinb,
                                          int b, int h, int s_base, int t,
                                          __bf16* dst, int tid)
{
    const int r  = tid >> 2;          // 0..63 row
    const int d0 = (tid & 3) * 16;    // 16 d-values per thread
    const int s  = s_base + r;
    const float* src = qkv + (((size_t)((size_t)b * SLEN + s) * 3 + t) * NH + h) * DH;
    const float* cs  = cosb + ((size_t)s * 3 + t) * DH;
    const float* sn  = sinb + ((size_t)s * 3 + t) * DH;
#pragma unroll
    for (int dd = 0; dd < 16; dd += 4) {
        const int d = d0 + dd;
        float4 f  = *(const float4*)(src + d);
        float4 g  = *(const float4*)(src + (d ^ 32));   // rotate_half partner
        float4 c4 = *(const float4*)(cs + d);
        float4 s4 = *(const float4*)(sn + d);
        const float sg = (d < 32) ? -1.f : 1.f;         // rotate_half sign
        union { __bf16 hv[4]; uint2 u; } pk;
        pk.hv[0] = (__bf16)(f.x * c4.x + sg * g.x * s4.x);
        pk.hv[1] = (__bf16)(f.y * c4.y + sg * g.y * s4.y);
        pk.hv[2] = (__bf16)(f.z * c4.z + sg * g.z * s4.z);
        pk.hv[3] = (__bf16)(f.w * c4.w + sg * g.w * s4.w);
        *(uint2*)(dst + r * LDK + d) = pk.u;
    }
}

__global__ __launch_bounds__(256)
void ddit_attn(const float* __restrict__ qkv,
               const float* __restrict__ cosb,
               const float* __restrict__ sinb,
               const int*   __restrict__ seqlens,
               float* __restrict__ out_x,
               float* __restrict__ out_logits)
{
    __shared__ __align__(16) __bf16 Klds[IT * LDK];        // K tile (also Q staging before loop)
    __shared__ __align__(16) __bf16 Vt[DH * LDK];          // V^T: [d][j_local]
    __shared__ __align__(16) __bf16 Pbuf[NWAVE * 16 * LDK];// per-wave P (C/D -> A layout transform)

    const int tid  = threadIdx.x;
    const int wave = tid >> 6;
    const int lane = tid & 63;
    const int qd   = lane >> 4;   // quad 0..3
    const int m    = lane & 15;

    const int nIt = SLEN / IT;
    const int it  = blockIdx.x % nIt;
    const int bh  = blockIdx.x / nIt;
    const int h   = bh % NH;
    const int b   = bh / NH;
    const int i0  = it * IT;
    const int len = seqlens[b];

    float* logits_base = out_logits + (size_t)bh * SLEN * SLEN;

    // ---- stage rotated Q tile into Klds, pull A-fragments ----
    stage_rot(qkv, cosb, sinb, b, h, i0, 0, Klds, tid);
    __syncthreads();
    bfx8 qfrag[2];
#pragma unroll
    for (int c = 0; c < 2; ++c)
        qfrag[c] = *(const bfx8*)&Klds[(wave * 16 + m) * LDK + c * 32 + qd * 8];
    // (loop-top barrier protects Klds before K staging overwrites it)

    // online-softmax state; rows of this wave: i0 + wave*16 + qd*4 + r
    float mrun[4], lrun[4];
    f32x4 acc[4];
#pragma unroll
    for (int r = 0; r < 4; ++r) { mrun[r] = -3.0e38f; lrun[r] = 0.f; }
#pragma unroll
    for (int c = 0; c < 4; ++c) acc[c] = (f32x4){0.f, 0.f, 0.f, 0.f};

    const int irow_base = i0 + wave * 16 + qd * 4;
    __bf16* myP = Pbuf + wave * 16 * LDK;

    for (int j0 = 0; j0 < SLEN; j0 += JT) {
        __syncthreads();  // previous tile's LDS reads complete
        stage_rot(qkv, cosb, sinb, b, h, j0, 1, Klds, tid);   // K (rotated)
        {   // V^T staging (v slice of rotary is identity)
            const int r  = tid >> 2;
            const int d0 = (tid & 3) * 16;
            const int s  = j0 + r;
            const float* src = qkv + (((size_t)((size_t)b * SLEN + s) * 3 + 2) * NH + h) * DH;
#pragma unroll
            for (int dd = 0; dd < 16; dd += 4) {
                float4 f = *(const float4*)(src + d0 + dd);
                Vt[(d0 + dd + 0) * LDK + r] = (__bf16)f.x;
                Vt[(d0 + dd + 1) * LDK + r] = (__bf16)f.y;
                Vt[(d0 + dd + 2) * LDK + r] = (__bf16)f.z;
                Vt[(d0 + dd + 3) * LDK + r] = (__bf16)f.w;
            }
        }
        __syncthreads();

        // ---- S = Q K^T for this wave's 16 rows x 64 cols ----
        f32x4 sacc[4];
#pragma unroll
        for (int t4 = 0; t4 < 4; ++t4) {
            sacc[t4] = (f32x4){0.f, 0.f, 0.f, 0.f};
#pragma unroll
            for (int c = 0; c < 2; ++c) {
                bfx8 kf = *(const bfx8*)&Klds[(t4 * 16 + m) * LDK + c * 32 + qd * 8];
                sacc[t4] = __builtin_amdgcn_mfma_f32_16x16x32_bf16(qfrag[c], kf, sacc[t4], 0, 0, 0);
            }
        }

        // ---- mask + write logits ----
        float ls[4][4];   // [t4][r]
#pragma unroll
        for (int t4 = 0; t4 < 4; ++t4) {
            const int jG = j0 + t4 * 16 + m;
            const bool vj = jG < len;
#pragma unroll
            for (int r = 0; r < 4; ++r) {
                const int iG = irow_base + r;
                const bool ok = vj && (iG < len);
                const float lv = ok ? sacc[t4][r] * 0.125f : -1.0e10f;
                ls[t4][r] = lv;
                logits_base[(size_t)iG * SLEN + jG] = lv;
            }
        }

        // ---- online softmax update + P to LDS ----
#pragma unroll
        for (int r = 0; r < 4; ++r) {
            float mt = fmaxf(fmaxf(ls[0][r], ls[1][r]), fmaxf(ls[2][r], ls[3][r]));
#pragma unroll
            for (int off = 1; off < 16; off <<= 1)
                mt = fmaxf(mt, __shfl_xor(mt, off));
            const float mn = fmaxf(mrun[r], mt);
            const float al = __expf(mrun[r] - mn);
            float p[4], ps = 0.f;
#pragma unroll
            for (int t4 = 0; t4 < 4; ++t4) { p[t4] = __expf(ls[t4][r] - mn); ps += p[t4]; }
#pragma unroll
            for (int off = 1; off < 16; off <<= 1)
                ps += __shfl_xor(ps, off);
            lrun[r] = lrun[r] * al + ps;
            mrun[r] = mn;
#pragma unroll
            for (int c = 0; c < 4; ++c) acc[c][r] *= al;
#pragma unroll
            for (int t4 = 0; t4 < 4; ++t4)
                myP[(qd * 4 + r) * LDK + t4 * 16 + m] = (__bf16)p[t4];
        }

        // ---- PV: acc += P * V  (A-frag from Pbuf, B-frag from Vt) ----
#pragma unroll
        for (int kc = 0; kc < 2; ++kc) {
            bfx8 pf = *(const bfx8*)&myP[m * LDK + kc * 32 + qd * 8];
#pragma unroll
            for (int c = 0; c < 4; ++c) {
                bfx8 vf = *(const bfx8*)&Vt[(c * 16 + m) * LDK + kc * 32 + qd * 8];
                acc[c] = __builtin_amdgcn_mfma_f32_16x16x32_bf16(pf, vf, acc[c], 0, 0, 0);
            }
        }
    }

    // ---- epilogue: x = acc / l ----
#pragma unroll
    for (int r = 0; r < 4; ++r) {
        const int iG = irow_base + r;
        const float inv = 1.f / lrun[r];
#pragma unroll
        for (int c = 0; c < 4; ++c)
            out_x[((size_t)bh * SLEN + iG) * DH + c * 16 + m] = acc[c][r] * inv;
    }
}

extern "C" void kernel_launch(void* const* d_in, const int* in_sizes, int n_in,
                              void* d_out, int out_size, void* d_ws, size_t ws_size,
                              hipStream_t stream) {
    const float* qkv     = (const float*)d_in[0];
    const float* cosb    = (const float*)d_in[1];
    const float* sinb    = (const float*)d_in[2];
    const int*   seqlens = (const int*)d_in[3];
    float* out_x      = (float*)d_out;
    float* out_logits = out_x + (size_t)NB * NH * SLEN * DH;

    dim3 grid(NB * NH * (SLEN / IT));
    dim3 block(256);
    ddit_attn<<<grid, block, 0, stream>>>(qkv, cosb, sinb, seqlens, out_x, out_logits);
}

// Round 2
// 583.574 us; speedup vs baseline: 1.0920x; 1.0920x over previous
//
#include <hip/hip_runtime.h>
#include <hip/hip_bf16.h>
#include <math.h>

// Problem constants (B,S,H,D fixed by the reference setup_inputs)
#define SLEN 2048
#define NH   12
#define NB   2
#define DH   64
#define IT   64          // i-rows per block
#define JT   64          // j-cols per tile
#define NWAVE 4
#define LDP  72          // P-buffer row stride (bf16 elems); 72*2B keeps 16B align, avoids 8-way banks

typedef __bf16 bfx8 __attribute__((ext_vector_type(8)));
typedef float  f32x4 __attribute__((ext_vector_type(4)));

// ---------------- pass 1: rotary + bf16 cast + V transpose ----------------
// grid: NB*NH*(SLEN/64) blocks, 256 threads.
// Outputs (in d_ws):
//   Qr[bh][s][d]  bf16   (rotary applied)
//   Kr[bh][s][d]  bf16   (rotary applied)
//   Vt[bh][d][s]  bf16   (v rotary slice is identity)
__global__ __launch_bounds__(256)
void ddit_prep(const float* __restrict__ qkv,
               const float* __restrict__ cosb,
               const float* __restrict__ sinb,
               __bf16* __restrict__ Qr, __bf16* __restrict__ Kr,
               __bf16* __restrict__ Vt)
{
    __shared__ __align__(16) __bf16 Vlds[64 * LDP];
    const int tid = threadIdx.x;
    const int nS  = SLEN / 64;
    const int s0  = (blockIdx.x % nS) * 64;
    const int bh  = blockIdx.x / nS;
    const int h   = bh % NH;
    const int b   = bh / NH;
    const int r   = tid >> 2;          // 0..63 row (s offset)
    const int d0  = (tid & 3) * 16;    // 16 d per thread
    const int s   = s0 + r;

    // Q (t=0) and K (t=1) with rotary
#pragma unroll
    for (int t = 0; t < 2; ++t) {
        const float* src = qkv + (((size_t)((size_t)b * SLEN + s) * 3 + t) * NH + h) * DH;
        const float* cs  = cosb + ((size_t)s * 3 + t) * DH;
        const float* sn  = sinb + ((size_t)s * 3 + t) * DH;
        union { __bf16 hv[16]; uint4 u4[2]; } pk;
#pragma unroll
        for (int dd = 0; dd < 16; dd += 4) {
            const int d = d0 + dd;
            float4 f  = *(const float4*)(src + d);
            float4 g  = *(const float4*)(src + (d ^ 32));
            float4 c4 = *(const float4*)(cs + d);
            float4 s4 = *(const float4*)(sn + d);
            const float sg = (d < 32) ? -1.f : 1.f;
            pk.hv[dd + 0] = (__bf16)(f.x * c4.x + sg * g.x * s4.x);
            pk.hv[dd + 1] = (__bf16)(f.y * c4.y + sg * g.y * s4.y);
            pk.hv[dd + 2] = (__bf16)(f.z * c4.z + sg * g.z * s4.z);
            pk.hv[dd + 3] = (__bf16)(f.w * c4.w + sg * g.w * s4.w);
        }
        __bf16* dst = (t == 0 ? Qr : Kr) + ((size_t)bh * SLEN + s) * DH + d0;
        *(uint4*)(dst + 0) = pk.u4[0];
        *(uint4*)(dst + 8) = pk.u4[1];
    }

    // V: stage to LDS, write out transposed
    {
        const float* src = qkv + (((size_t)((size_t)b * SLEN + s) * 3 + 2) * NH + h) * DH;
#pragma unroll
        for (int dd = 0; dd < 16; dd += 4) {
            float4 f = *(const float4*)(src + d0 + dd);
            union { __bf16 hv[4]; uint2 u; } pk;
            pk.hv[0] = (__bf16)f.x; pk.hv[1] = (__bf16)f.y;
            pk.hv[2] = (__bf16)f.z; pk.hv[3] = (__bf16)f.w;
            *(uint2*)(Vlds + r * LDP + d0 + dd) = pk.u;
        }
    }
    __syncthreads();
    {
        const int dv   = tid >> 2;         // 0..63: d row of Vt
        const int soff = (tid & 3) * 16;   // 16 s per thread
        union { __bf16 hv[16]; uint4 u4[2]; } pk;
#pragma unroll
        for (int j = 0; j < 16; ++j)
            pk.hv[j] = Vlds[(soff + j) * LDP + dv];
        __bf16* dst = Vt + ((size_t)bh * DH + dv) * SLEN + s0 + soff;
        *(uint4*)(dst + 0) = pk.u4[0];
        *(uint4*)(dst + 8) = pk.u4[1];
    }
}

// ---------------- pass 2: barrier-free fused attention ----------------
__global__ __launch_bounds__(256)
void ddit_attn(const __bf16* __restrict__ Qr,
               const __bf16* __restrict__ Kr,
               const __bf16* __restrict__ Vt,
               const int*   __restrict__ seqlens,
               float* __restrict__ out_x,
               float* __restrict__ out_logits)
{
    __shared__ __align__(16) __bf16 Pbuf[NWAVE * 16 * LDP]; // per-wave, no barrier needed

    const int tid  = threadIdx.x;
    const int wave = tid >> 6;
    const int lane = tid & 63;
    const int qd   = lane >> 4;   // quad 0..3
    const int m    = lane & 15;

    // XCD swizzle: keep all 32 i-blocks of one bh on the same XCD (L2 locality)
    const int nIt   = SLEN / IT;                    // 32
    const int gridN = NB * NH * nIt;                // 768
    const int bid   = blockIdx.x;
    const int nid   = (bid & 7) * (gridN >> 3) + (bid >> 3);
    const int it    = nid % nIt;
    const int bh    = nid / nIt;
    const int b     = bh / NH;
    const int i0    = it * IT;
    const int len   = seqlens[b];

    const __bf16* Qb = Qr + (size_t)bh * SLEN * DH;
    const __bf16* Kb = Kr + (size_t)bh * SLEN * DH;
    const __bf16* Vb = Vt + (size_t)bh * DH * SLEN;
    float* logits_base = out_logits + (size_t)bh * SLEN * SLEN;

    // Q A-fragments straight from global (L2-resident after prep)
    bfx8 qfrag[2];
#pragma unroll
    for (int c = 0; c < 2; ++c)
        qfrag[c] = *(const bfx8*)(Qb + (size_t)(i0 + wave * 16 + m) * DH + c * 32 + qd * 8);

    float mrun[4], lrun[4];
    f32x4 acc[4];
#pragma unroll
    for (int r = 0; r < 4; ++r) { mrun[r] = -3.0e38f; lrun[r] = 0.f; }
#pragma unroll
    for (int c = 0; c < 4; ++c) acc[c] = (f32x4){0.f, 0.f, 0.f, 0.f};

    const int irow_base = i0 + wave * 16 + qd * 4;
    __bf16* myP = Pbuf + wave * 16 * LDP;

    for (int j0 = 0; j0 < SLEN; j0 += JT) {
        // ---- K fragments direct from global ----
        bfx8 kf[4][2];
#pragma unroll
        for (int t4 = 0; t4 < 4; ++t4)
#pragma unroll
            for (int c = 0; c < 2; ++c)
                kf[t4][c] = *(const bfx8*)(Kb + (size_t)(j0 + t4 * 16 + m) * DH + c * 32 + qd * 8);

        // ---- S = Q K^T ----
        f32x4 sacc[4];
#pragma unroll
        for (int t4 = 0; t4 < 4; ++t4) {
            sacc[t4] = (f32x4){0.f, 0.f, 0.f, 0.f};
#pragma unroll
            for (int c = 0; c < 2; ++c)
                sacc[t4] = __builtin_amdgcn_mfma_f32_16x16x32_bf16(qfrag[c], kf[t4][c], sacc[t4], 0, 0, 0);
        }

        // ---- V fragments issued early: softmax below hides their latency ----
        bfx8 vf[2][4];
#pragma unroll
        for (int kc = 0; kc < 2; ++kc)
#pragma unroll
            for (int c = 0; c < 4; ++c)
                vf[kc][c] = *(const bfx8*)(Vb + (size_t)(c * 16 + m) * SLEN + j0 + kc * 32 + qd * 8);

        // ---- mask + write logits ----
        float ls[4][4];   // [t4][r]
#pragma unroll
        for (int t4 = 0; t4 < 4; ++t4) {
            const int jG = j0 + t4 * 16 + m;
            const bool vj = jG < len;
#pragma unroll
            for (int r = 0; r < 4; ++r) {
                const int iG = irow_base + r;
                const bool ok = vj && (iG < len);
                const float lv = ok ? sacc[t4][r] * 0.125f : -1.0e10f;
                ls[t4][r] = lv;
                logits_base[(size_t)iG * SLEN + jG] = lv;
            }
        }

        // ---- online softmax + P to per-wave LDS ----
#pragma unroll
        for (int r = 0; r < 4; ++r) {
            float mt = fmaxf(fmaxf(ls[0][r], ls[1][r]), fmaxf(ls[2][r], ls[3][r]));
#pragma unroll
            for (int off = 1; off < 16; off <<= 1)
                mt = fmaxf(mt, __shfl_xor(mt, off));
            const float mn = fmaxf(mrun[r], mt);
            const float al = __expf(mrun[r] - mn);
            float p[4], ps = 0.f;
#pragma unroll
            for (int t4 = 0; t4 < 4; ++t4) { p[t4] = __expf(ls[t4][r] - mn); ps += p[t4]; }
#pragma unroll
            for (int off = 1; off < 16; off <<= 1)
                ps += __shfl_xor(ps, off);
            lrun[r] = lrun[r] * al + ps;
            mrun[r] = mn;
#pragma unroll
            for (int c = 0; c < 4; ++c) acc[c][r] *= al;
#pragma unroll
            for (int t4 = 0; t4 < 4; ++t4)
                myP[(qd * 4 + r) * LDP + t4 * 16 + m] = (__bf16)p[t4];
        }

        // ---- PV (A-frag from per-wave Pbuf; DS ops are in-order per wave) ----
#pragma unroll
        for (int kc = 0; kc < 2; ++kc) {
            bfx8 pf = *(const bfx8*)&myP[m * LDP + kc * 32 + qd * 8];
#pragma unroll
            for (int c = 0; c < 4; ++c)
                acc[c] = __builtin_amdgcn_mfma_f32_16x16x32_bf16(pf, vf[kc][c], acc[c], 0, 0, 0);
        }
    }

    // ---- epilogue: x = acc / l ----
#pragma unroll
    for (int r = 0; r < 4; ++r) {
        const int iG = irow_base + r;
        const float inv = 1.f / lrun[r];
#pragma unroll
        for (int c = 0; c < 4; ++c)
            out_x[((size_t)bh * SLEN + iG) * DH + c * 16 + m] = acc[c][r] * inv;
    }
}

extern "C" void kernel_launch(void* const* d_in, const int* in_sizes, int n_in,
                              void* d_out, int out_size, void* d_ws, size_t ws_size,
                              hipStream_t stream) {
    const float* qkv     = (const float*)d_in[0];
    const float* cosb    = (const float*)d_in[1];
    const float* sinb    = (const float*)d_in[2];
    const int*   seqlens = (const int*)d_in[3];
    float* out_x      = (float*)d_out;
    float* out_logits = out_x + (size_t)NB * NH * SLEN * DH;

    const size_t perT = (size_t)NB * NH * SLEN * DH;   // 3.1M elems bf16 each
    __bf16* Qr = (__bf16*)d_ws;
    __bf16* Kr = Qr + perT;
    __bf16* Vt = Kr + perT;

    dim3 block(256);
    ddit_prep<<<dim3(NB * NH * (SLEN / 64)), block, 0, stream>>>(qkv, cosb, sinb, Qr, Kr, Vt);
    ddit_attn<<<dim3(NB * NH * (SLEN / IT)), block, 0, stream>>>(Qr, Kr, Vt, seqlens, out_x, out_logits);
}